// Round 14
// baseline (255.497 us; speedup 1.0000x reference)
//
#include <hip/hip_runtime.h>

#define N_NODES 50000
#define C_FEAT  64
#define E_EDGES 800000
#define KEYS    400000          // dst*8 + t
#define NBLK1   391             // ceil(KEYS/1024)
#define DPB     16              // dsts per conv tile -> 16 MFMA rows
#define NTILES  (N_NODES / DPB) // 3125
#define PBLK_X  1563            // x->bf16 cvt blocks (8 elems/thread, last partial)
#define PBLK_W  128             // Wt transpose blocks
#define PBLK_A  64              // Wa1T/Wa2T transpose blocks (2 x 8192)
#define PBLK_H  782             // hist+rank blocks: 4 edges/thread (1024/block)

typedef __attribute__((ext_vector_type(8))) short short8;
typedef __attribute__((ext_vector_type(4))) float f32x4;

__device__ __forceinline__ float bf2f(unsigned short u) {
    union { unsigned int i; float f; } v; v.i = ((unsigned int)u) << 16; return v.f;
}
__device__ __forceinline__ unsigned short f2bf(float f) {
    union { float f; unsigned int i; } v; v.f = f;
    unsigned int r = v.i + 0x7fff + ((v.i >> 16) & 1);   // RNE
    return (unsigned short)(r >> 16);
}

// -------- prep (x->bf16, Wt->WT bf16, Wa->WaT bf16) + hist WITH rank records --------
__global__ __launch_bounds__(256) void prep_hist(const float* __restrict__ x,
                                                 const float* __restrict__ W1,
                                                 const float* __restrict__ W2,
                                                 const float* __restrict__ Wa1,
                                                 const float* __restrict__ Wa2,
                                                 const int* __restrict__ src,
                                                 const int* __restrict__ dst,
                                                 const int* __restrict__ tix,
                                                 unsigned short* __restrict__ xb,
                                                 unsigned short* __restrict__ WT1,
                                                 unsigned short* __restrict__ WT2,
                                                 unsigned short* __restrict__ Wa1T,
                                                 unsigned short* __restrict__ Wa2T,
                                                 int* __restrict__ cnt,
                                                 int2* __restrict__ rec) {
    const int b = blockIdx.x;
    if (b < PBLK_X) {
        int base = (b * 256 + threadIdx.x) * 8;
        if (base < N_NODES * 64) {
            float4 a = *(const float4*)(x + base);
            float4 c = *(const float4*)(x + base + 4);
            short8 o;
            o[0] = (short)f2bf(a.x); o[1] = (short)f2bf(a.y);
            o[2] = (short)f2bf(a.z); o[3] = (short)f2bf(a.w);
            o[4] = (short)f2bf(c.x); o[5] = (short)f2bf(c.y);
            o[6] = (short)f2bf(c.z); o[7] = (short)f2bf(c.w);
            *(short8*)(xb + base) = o;
        }
    } else if (b < PBLK_X + PBLK_W) {
        int i = (b - PBLK_X) * 256 + threadIdx.x;      // 32768
        int n = i >> 9, k = i & 511;
        WT1[i] = f2bf(W1[k * 64 + n]);
        WT2[i] = f2bf(W2[k * 64 + n]);
    } else if (b < PBLK_X + PBLK_W + PBLK_A) {
        int i = (b - PBLK_X - PBLK_W) * 256 + threadIdx.x;   // 0..16383
        if (i < 8192) {                                // Wa1T[128][64] <- Wa1[64][128]
            int n = i >> 6, k = i & 63;
            Wa1T[i] = f2bf(Wa1[k * 128 + n]);
        } else {                                       // Wa2T[64][128] <- Wa2[128][64]
            int ii = i - 8192;
            int n = ii >> 7, k = ii & 127;
            Wa2T[ii] = f2bf(Wa2[k * 64 + n]);
        }
    } else {
        // hist + rank: every edge visited once, 4 edges/thread
        int bb = b - PBLK_X - PBLK_W - PBLK_A;         // 0..781
        const int e0 = bb * 1024 + threadIdx.x * 4;
        if (e0 < E_EDGES) {                            // E%4==0 -> window fully in-bounds
            int4 d = *(const int4*)(dst + e0);
            int4 t = *(const int4*)(tix + e0);
            int4 s = *(const int4*)(src + e0);
            int dd[4] = {d.x, d.y, d.z, d.w};
            int tt[4] = {t.x, t.y, t.z, t.w};
            int ss[4] = {s.x, s.y, s.z, s.w};
            int rk[4];
            #pragma unroll
            for (int k = 0; k < 4; ++k)                // 4 independent atomics in flight
                rk[k] = atomicAdd(&cnt[dd[k] * 8 + tt[k]], 1);
            #pragma unroll
            for (int k = 0; k < 4; ++k)                // coalesced 32B/thread rec store
                rec[e0 + k] = make_int2(ss[k] | (tt[k] << 16) | ((dd[k] & 15) << 19),
                                        (dd[k] * 8 + tt[k]) | (rk[k] << 19));
        }
    }
}

// -------- scan_all: per-chunk local scan; LAST block scans chunk totals --------
__global__ __launch_bounds__(256) void scan_all(int* __restrict__ cnt,
                                                int* __restrict__ bsum,
                                                int* __restrict__ chunkoff,
                                                int* __restrict__ done) {
    __shared__ int wsum[4];
    __shared__ int ticket;
    const int tid = threadIdx.x;
    const int lane = tid & 63;
    const int wave = tid >> 6;
    const int i4 = blockIdx.x * 256 + tid;
    int4 v = make_int4(0, 0, 0, 0);
    const bool ok = (i4 * 4 < KEYS);
    if (ok) v = ((const int4*)cnt)[i4];
    int s = v.x + v.y + v.z + v.w;
    int sc = s;
    #pragma unroll
    for (int d = 1; d < 64; d <<= 1) {
        int o = __shfl_up(sc, d, 64);
        if (lane >= d) sc += o;
    }
    if (lane == 63) wsum[wave] = sc;
    __syncthreads();
    int wbase = 0;
    #pragma unroll
    for (int w = 0; w < 4; ++w) wbase += (w < wave) ? wsum[w] : 0;
    int base = wbase + sc - s;
    int4 o;
    o.x = base;
    o.y = base + v.x;
    o.z = o.y + v.y;
    o.w = o.z + v.z;
    if (ok) ((int4*)cnt)[i4] = o;
    if (tid == 255) {
        bsum[blockIdx.x] = wbase + sc;
        __threadfence();
        ticket = atomicAdd(done, 1);
    }
    __syncthreads();
    if (ticket == NBLK1 - 1 && wave == 0) {
        int carry = 0;
        #pragma unroll
        for (int g = 0; g < (NBLK1 + 63) / 64; ++g) {
            int j = g * 64 + lane;
            int val = (j < NBLK1) ? atomicAdd(&bsum[j], 0) : 0;
            int scn = val;
            #pragma unroll
            for (int d = 1; d < 64; d <<= 1) {
                int oo = __shfl_up(scn, d, 64);
                if (lane >= d) scn += oo;
            }
            if (j < NBLK1) chunkoff[j] = carry + scn - val;
            carry += __shfl(scn, 63, 64);
        }
    }
}

// -------- rank-based scatter: NO atomics, fire-and-forget --------
__global__ __launch_bounds__(256) void scatter_rank(const int2* __restrict__ rec,
                                                    const int* __restrict__ cnt,
                                                    const int* __restrict__ chunkoff,
                                                    int* __restrict__ elist) {
    const int i = (blockIdx.x * 256 + threadIdx.x) * 2;
    if (i < E_EDGES) {                               // E%2==0 -> pair in-bounds
        int4 r = *(const int4*)(rec + i);            // recs i, i+1
        int key0 = r.y & 0x7ffff, rank0 = (int)((unsigned)r.y >> 19);
        int key1 = r.w & 0x7ffff, rank1 = (int)((unsigned)r.w >> 19);
        elist[chunkoff[key0 >> 10] + cnt[key0] + rank0] = r.x;
        elist[chunkoff[key1 >> 10] + cnt[key1] + rank1] = r.z;
    }
}

// -------- fused conv: quarter-wave streams -- 4 edges per wave-op --------
// Each wave owns 4 dsts; QUARTER q (16 lanes) owns dst 4w+q and processes its
// whole key-sorted stream sequentially with the run-length accumulator (plain
// LDS stores -- streams align to dst boundaries so rows are quarter-private;
// NOT R1's LDS-atomic scheme). Lane holds 4 cols (uint2 = 8B, 16 lanes = full
// 128B row); one EDGE step = 4 edges wave-wide. Invalid steps (stream shorter
// than wave max) load row 0, value zeroed, key forced to cur -> no-op add.
#define STORE_ACC                                                                     \
    { unsigned int o0 = (unsigned)f2bf(acc0) | ((unsigned)f2bf(acc1) << 16);          \
      unsigned int o1 = (unsigned)f2bf(acc2) | ((unsigned)f2bf(acc3) << 16);          \
      uint2 ov; ov.x = o0; ov.y = o1;                                                 \
      *(uint2*)&scat[cur >> 3][((cur & 7) << 6) + (cl << 2)] = ov; }

#define EDGE(K)                                                                       \
    int p##K = __shfl(pv, bq + (K), 64);                                              \
    const bool ok##K = (i + (K)) < len;                                               \
    uint2 u##K = *(const uint2*)(Xb + ((size_t)(unsigned)(ok##K ? (p##K & 0xffff) : 0) << 6) + (cl << 2)); \
    if (!ok##K) { u##K.x = 0; u##K.y = 0; }

#define FLUSH(K)                                                                      \
    { int _k = ok##K ? (p##K >> 16) : cur;                                            \
      if (_k != cur) { STORE_ACC; acc0 = acc1 = acc2 = acc3 = 0.f; cur = _k; }        \
      acc0 += bf2f((unsigned short)(u##K.x));                                         \
      acc1 += bf2f((unsigned short)(u##K.x >> 16));                                   \
      acc2 += bf2f((unsigned short)(u##K.y));                                         \
      acc3 += bf2f((unsigned short)(u##K.y >> 16)); }

template <bool ADV>
__global__ __launch_bounds__(256, 6) void fused_conv(const unsigned short* __restrict__ Xb,
                                                     const unsigned short* __restrict__ WT,
                                                     const float* __restrict__ bias,
                                                     const int* __restrict__ cstart,   // start offsets
                                                     const int* __restrict__ chunkoff,
                                                     const int* __restrict__ elist,
                                                     unsigned short* __restrict__ Hb,
                                                     const unsigned short* __restrict__ Wa1T,
                                                     const float* __restrict__ ba1,
                                                     const unsigned short* __restrict__ Wa2T,
                                                     const float* __restrict__ ba2,
                                                     const unsigned short* __restrict__ h1r,
                                                     float* __restrict__ outF) {
    __shared__ __attribute__((aligned(16))) unsigned short scat[DPB][520];
    // adv-phase aliases over the scat pool (used only after a barrier)
    unsigned short (*sH)[72]  = (unsigned short(*)[72])&scat[0][0];          // 2304 B
    unsigned short (*sT)[136] = (unsigned short(*)[136])((char*)scat + 4096); // 4352 B
    const int lane = threadIdx.x & 63;
    const int wave = threadIdx.x >> 6;               // 0..3
    const int cl = lane & 15;                        // col-slot within quarter
    const int bq = lane & 48;                        // quarter base lane
    const int dbase = blockIdx.x * DPB;

    {   // zero own 4 rows
        short8 z = {};
        *(short8*)&scat[wave * 4 + 0][lane * 8] = z;
        *(short8*)&scat[wave * 4 + 1][lane * 8] = z;
        *(short8*)&scat[wave * 4 + 2][lane * 8] = z;
        *(short8*)&scat[wave * 4 + 3][lane * 8] = z;
    }

    // quarter stream: dst = dbase + wave*4 + (lane>>4)
    const int dq = dbase + wave * 4 + (lane >> 4);
    const int kq = dq * 8;
    const int kqe = kq + 8;
    const int qbeg = chunkoff[kq >> 10] + cstart[kq];
    const int qend = (kqe >= KEYS) ? E_EDGES : chunkoff[kqe >> 10] + cstart[kqe];
    const int len = qend - qbeg;

    // wave-uniform loop bound: max of the 4 quarter lengths
    int l0 = __builtin_amdgcn_readlane(len, 0);
    int l1 = __builtin_amdgcn_readlane(len, 16);
    int l2 = __builtin_amdgcn_readlane(len, 32);
    int l3 = __builtin_amdgcn_readlane(len, 48);
    const int maxw = max(max(l0, l1), max(l2, l3));

    int pv = (cl < len) ? elist[qbeg + cl] : 0;      // first 16 edges of quarter
    int cur = 0;
    float acc0 = 0.f, acc1 = 0.f, acc2 = 0.f, acc3 = 0.f;
    if (len > 0) cur = __shfl(pv, bq, 64) >> 16;

    for (int i = 0; i < maxw; i += 16) {
        // hoisted refill of next 16-edge chunk (overlaps processing below)
        int pvn = 0;
        {
            int nx = i + 16 + cl;
            if (nx < len) pvn = elist[qbeg + nx];
        }
        EDGE(0)  EDGE(1)  EDGE(2)  EDGE(3)
        EDGE(4)  EDGE(5)  EDGE(6)  EDGE(7)
        EDGE(8)  EDGE(9)  EDGE(10) EDGE(11)
        EDGE(12) EDGE(13) EDGE(14) EDGE(15)
        FLUSH(0)  FLUSH(1)  FLUSH(2)  FLUSH(3)
        FLUSH(4)  FLUSH(5)  FLUSH(6)  FLUSH(7)
        FLUSH(8)  FLUSH(9)  FLUSH(10) FLUSH(11)
        FLUSH(12) FLUSH(13) FLUSH(14) FLUSH(15)
        pv = pvn;
    }
    if (len > 0) STORE_ACC;
    __syncthreads();

    // MFMA [16,512]@[512,64] on all 4 waves; C/D col=lane&15, row=quad*4+r (m89/m91)
    const int m = lane & 15;
    const int quad = lane >> 4;
    f32x4 acc4 = {0.f, 0.f, 0.f, 0.f};
    {
        const int n0 = wave * 16;
        const unsigned short* wrow = WT + (size_t)(n0 + m) * 512;
        #pragma unroll
        for (int kc = 0; kc < 16; ++kc) {
            short8 af = *(const short8*)&scat[m][kc * 32 + quad * 8];
            short8 bf = *(const short8*)(wrow + kc * 32 + quad * 8);
            acc4 = __builtin_amdgcn_mfma_f32_16x16x32_bf16(af, bf, acc4, 0, 0, 0);
        }
    }

    if (!ADV) {
        const int col = wave * 16 + m;
        const float bcol = bias[col];
        #pragma unroll
        for (int r = 0; r < 4; ++r) {
            int node = dbase + quad * 4 + r;
            Hb[(size_t)node * 64 + col] = f2bf(fmaxf(acc4[r] + bcol, 0.f));
        }
    } else {
        // ---- fused adversary MLP on this tile's 16 nodes ----
        __syncthreads();                     // all scat MFMA reads complete
        {                                    // h2 (relu'd, bf16) -> sH
            const int col = wave * 16 + m;
            const float bcol = bias[col];
            #pragma unroll
            for (int r = 0; r < 4; ++r)
                sH[quad * 4 + r][col] = f2bf(fmaxf(acc4[r] + bcol, 0.f));
        }
        __syncthreads();
        {   // GEMM1: [16,64]@[64,128]; 4 waves x two 16-col tiles
            #pragma unroll
            for (int ct = 0; ct < 2; ++ct) {
                f32x4 a1 = {0.f, 0.f, 0.f, 0.f};
                const int col = (wave * 2 + ct) * 16 + m;
                #pragma unroll
                for (int kc = 0; kc < 2; ++kc) {
                    short8 af = *(const short8*)&sH[m][kc * 32 + quad * 8];
                    short8 bf = *(const short8*)(Wa1T + (size_t)col * 64 + kc * 32 + quad * 8);
                    a1 = __builtin_amdgcn_mfma_f32_16x16x32_bf16(af, bf, a1, 0, 0, 0);
                }
                const float b1 = ba1[col];
                #pragma unroll
                for (int r = 0; r < 4; ++r)
                    sT[quad * 4 + r][col] = f2bf(fmaxf(a1[r] + b1, 0.f));
            }
        }
        __syncthreads();
        {   // GEMM2: [16,128]@[128,64]; 4 waves x one 16-col tile; + ba2 + h1
            f32x4 a2 = {0.f, 0.f, 0.f, 0.f};
            const int col = wave * 16 + m;
            #pragma unroll
            for (int kc = 0; kc < 4; ++kc) {
                short8 af = *(const short8*)&sT[m][kc * 32 + quad * 8];
                short8 bf = *(const short8*)(Wa2T + (size_t)col * 128 + kc * 32 + quad * 8);
                a2 = __builtin_amdgcn_mfma_f32_16x16x32_bf16(af, bf, a2, 0, 0, 0);
            }
            const float b2 = ba2[col];
            #pragma unroll
            for (int r = 0; r < 4; ++r) {
                int node = dbase + quad * 4 + r;
                outF[(size_t)node * 64 + col] =
                    a2[r] + b2 + bf2f(h1r[(size_t)node * 64 + col]);
            }
        }
    }
}

extern "C" void kernel_launch(void* const* d_in, const int* in_sizes, int n_in,
                              void* d_out, int out_size, void* d_ws, size_t ws_size,
                              hipStream_t stream) {
    const float* x   = (const float*)d_in[0];
    const int*   ei  = (const int*)d_in[1];
    const int*   tix = (const int*)d_in[2];
    const float* Wt1 = (const float*)d_in[3];
    const float* bt1 = (const float*)d_in[4];
    const float* Wt2 = (const float*)d_in[5];
    const float* bt2 = (const float*)d_in[6];
    const float* Wa1 = (const float*)d_in[7];
    const float* ba1 = (const float*)d_in[8];
    const float* Wa2 = (const float*)d_in[9];
    const float* ba2 = (const float*)d_in[10];
    float* out = (float*)d_out;

    const int* src = ei;
    const int* dst = ei + E_EDGES;

    // workspace (~32 MB)
    unsigned short* xb   = (unsigned short*)d_ws;          // [N,64] bf16
    unsigned short* h1b  = xb + (size_t)N_NODES * 64;      // [N,64] bf16
    unsigned short* h2b  = h1b + (size_t)N_NODES * 64;     // [N,64] bf16 (unused)
    unsigned short* WT1  = h2b + (size_t)N_NODES * 64;     // [64,512] bf16
    unsigned short* WT2  = WT1 + 64 * 512;
    unsigned short* Wa1T = WT2 + 64 * 512;                 // [128,64] bf16
    unsigned short* Wa2T = Wa1T + 8192;                    // [64,128] bf16
    int* cnt      = (int*)(Wa2T + 8192);                   // KEYS
    int* bsum     = cnt + KEYS;                            // 512
    int* chunkoff = bsum + 512;                            // 512
    int* done     = chunkoff + 512;                        // 64 (1 used)
    int* elist    = done + 64;                             // E packed (src | t<<16 | dl<<19)
    int2* rec     = (int2*)(elist + E_EDGES);              // E records (payload, key|rank<<19)

    hipMemsetAsync(cnt, 0, (KEYS + 512 + 512 + 64) * sizeof(int), stream);
    prep_hist<<<PBLK_X + PBLK_W + PBLK_A + PBLK_H, 256, 0, stream>>>(
        x, Wt1, Wt2, Wa1, Wa2, src, dst, tix, xb, WT1, WT2, Wa1T, Wa2T, cnt, rec);
    scan_all<<<NBLK1, 256, 0, stream>>>(cnt, bsum, chunkoff, done);
    scatter_rank<<<(E_EDGES / 2 + 255) / 256, 256, 0, stream>>>(rec, cnt, chunkoff, elist);

    fused_conv<false><<<NTILES, 256, 0, stream>>>(
        xb, WT1, bt1, cnt, chunkoff, elist, h1b,
        nullptr, nullptr, nullptr, nullptr, nullptr, nullptr);
    fused_conv<true><<<NTILES, 256, 0, stream>>>(
        h1b, WT2, bt2, cnt, chunkoff, elist, nullptr,
        Wa1T, ba1, Wa2T, ba2, h1b, out);
}